// Round 9
// baseline (997.902 us; speedup 1.0000x reference)
//
#include <hip/hip_runtime.h>

#define N_NODES 50000
#define N_EDGES 600000
#define D 128
#define SCAN_BLOCKS ((N_NODES + 255) / 256)   // 196

typedef __attribute__((ext_vector_type(8))) short bf16x8;
typedef __attribute__((ext_vector_type(4))) float floatx4;

__device__ inline unsigned int f2bf(float f) {
    unsigned int u = __float_as_uint(f);
    return (u + 0x7FFFu + ((u >> 16) & 1u)) >> 16;   // RNE
}
__device__ inline float bf_lo(unsigned int u) { return __uint_as_float(u << 16); }
__device__ inline float bf_hi(unsigned int u) { return __uint_as_float(u & 0xFFFF0000u); }

// ---------------- fused prep: cvt x -> bf16, cvt W -> bf16, degree count ----
__global__ void k_prep(const float* __restrict__ x, unsigned short* __restrict__ xbf,
                       const float* __restrict__ wa, const float* __restrict__ wb,
                       const float* __restrict__ wc, const float* __restrict__ wd,
                       unsigned short* __restrict__ wbf,
                       const int* __restrict__ dst, int* __restrict__ cnt) {
    const int b = blockIdx.x;
    const int t = threadIdx.x;
    if (b < 6250) {
        int i = b * 256 + t;
        float4 v = ((const float4*)x)[i];
        uint2 o;
        o.x = f2bf(v.x) | (f2bf(v.y) << 16);
        o.y = f2bf(v.z) | (f2bf(v.w) << 16);
        ((uint2*)xbf)[i] = o;
    } else if (b < 6506) {
        int i = (b - 6250) * 256 + t;
        const float* srcs[4] = {wa, wb, wc, wd};
        wbf[i] = (unsigned short)f2bf(srcs[i >> 14][i & 16383]);
    } else {
        int e = (b - 6506) * 256 + t;
        if (e < N_EDGES) atomicAdd(&cnt[dst[e]], 1);
    }
}

// ---------------- CSR scan + bucket ----------------

__global__ void k_scan1(const int* __restrict__ cnt, int* __restrict__ off,
                        int* __restrict__ partial) {
    __shared__ int sdata[256];
    const int t = threadIdx.x;
    const int i = blockIdx.x * 256 + t;
    int v = (i < N_NODES) ? cnt[i] : 0;
    sdata[t] = v;
    __syncthreads();
    for (int d = 1; d < 256; d <<= 1) {
        int u = (t >= d) ? sdata[t - d] : 0;
        __syncthreads();
        sdata[t] += u;
        __syncthreads();
    }
    if (i < N_NODES) off[i] = sdata[t] - v;
    if (t == 255) partial[blockIdx.x] = sdata[255];
}

__global__ void k_scan2(int* __restrict__ partial) {
    __shared__ int sdata[256];
    const int t = threadIdx.x;
    int v = (t < SCAN_BLOCKS) ? partial[t] : 0;
    sdata[t] = v;
    __syncthreads();
    for (int d = 1; d < 256; d <<= 1) {
        int u = (t >= d) ? sdata[t - d] : 0;
        __syncthreads();
        sdata[t] += u;
        __syncthreads();
    }
    if (t < SCAN_BLOCKS) partial[t] = sdata[t] - v;
}

__global__ void k_scan3(int* __restrict__ off, const int* __restrict__ partial,
                        int* __restrict__ cursor) {
    const int i = blockIdx.x * 256 + threadIdx.x;
    if (i < N_NODES) {
        int o = off[i] + partial[blockIdx.x];
        off[i] = o;
        cursor[i] = o;
    }
    if (i == 0) off[N_NODES] = N_EDGES;
}

__global__ void k_bucket(const int* __restrict__ src, const int* __restrict__ dst,
                         int* __restrict__ cursor, int* __restrict__ ebuf) {
    int e = blockIdx.x * blockDim.x + threadIdx.x;
    if (e < N_EDGES) {
        int p = atomicAdd(&cursor[dst[e]], 1);
        ebuf[p] = src[e];
    }
}

// ---------------- fused gather + MFMA layer ----------------
// Block = 256 threads = 16 nodes.
// Phase 1 (edge-parallel gather): the block's whole edge range is flattened to
//   (edge, 16B-chunk) items strided across all 256 threads -> perfect balance,
//   independent iterations (max MLP). Accumulate fp32 via LDS atomicAdd
//   (ds_add_f32; same-(q,j) lanes differ in nl -> mostly 2-way = free).
//   Node of an edge: 4-step binary search in the 17-entry LDS offset table.
// Phase 2 (MFMA): unchanged from R7 (validated): wave wv = feats [32wv,32wv+32),
//   A(mean) from LDS bf16 tile, A(x)/B(W rows) from global.
template <bool RELU, bool OUT_BF16>
__global__ void __launch_bounds__(256) k_gather_layer(
    const int* __restrict__ off, const int* __restrict__ ebuf,
    const unsigned short* __restrict__ Xbf,
    const unsigned short* __restrict__ Wlbf, const float* __restrict__ bias,
    const unsigned short* __restrict__ Wrbf, void* __restrict__ outp) {
    __shared__ int s_off[17];
    __shared__ float accf[16][132];
    __shared__ unsigned short tile[16][136];

    const int t = threadIdx.x;
    const int node0 = blockIdx.x * 16;

    if (t < 17) s_off[t] = off[node0 + t];
    for (int i = t; i < 16 * 132; i += 256) ((float*)accf)[i] = 0.f;
    __syncthreads();

    // ---- phase 1: balanced edge-parallel gather ----
    {
        const int e0 = s_off[0];
        const int items = (s_off[16] - e0) * 16;
        const int q = t & 15;          // fixed chunk per thread (it & 15 == t & 15)
#pragma unroll 2
        for (int it = t; it < items; it += 256) {
            int eidx = e0 + (it >> 4);
            int s = ebuf[eidx];
            uint4 v = *(const uint4*)(Xbf + (size_t)s * D + q * 8);
            int nl = 0;
#pragma unroll
            for (int step = 8; step >= 1; step >>= 1)
                if (s_off[nl + step] <= eidx) nl += step;
            float* arow = &accf[nl][q * 8];
            atomicAdd(arow + 0, bf_lo(v.x));
            atomicAdd(arow + 1, bf_hi(v.x));
            atomicAdd(arow + 2, bf_lo(v.y));
            atomicAdd(arow + 3, bf_hi(v.y));
            atomicAdd(arow + 4, bf_lo(v.z));
            atomicAdd(arow + 5, bf_hi(v.z));
            atomicAdd(arow + 6, bf_lo(v.w));
            atomicAdd(arow + 7, bf_hi(v.w));
        }
    }
    __syncthreads();

    // ---- normalize -> bf16 tile ----
    {
        const int nl = t >> 4, q = t & 15;
        int deg = s_off[nl + 1] - s_off[nl];
        float inv = (deg > 0) ? 1.0f / (float)deg : 0.0f;
        const float* a = &accf[nl][q * 8];
        uint4 o;
        o.x = f2bf(a[0] * inv) | (f2bf(a[1] * inv) << 16);
        o.y = f2bf(a[2] * inv) | (f2bf(a[3] * inv) << 16);
        o.z = f2bf(a[4] * inv) | (f2bf(a[5] * inv) << 16);
        o.w = f2bf(a[6] * inv) | (f2bf(a[7] * inv) << 16);
        *(uint4*)(&tile[nl][q * 8]) = o;
    }
    __syncthreads();

    // ---- phase 2: MFMA ----
    const int lane = t & 63;
    const int wv = t >> 6;
    const int l15 = lane & 15;
    const int quad = lane >> 4;

    floatx4 c0 = (floatx4)(0.f), c1 = (floatx4)(0.f);
    const int nf0 = wv * 2, nf1 = wv * 2 + 1;

    const unsigned short* mrow = &tile[l15][quad * 8];
    const unsigned short* arowX = Xbf + (size_t)(node0 + l15) * D + quad * 8;

#pragma unroll
    for (int kk = 0; kk < 4; ++kk) {
        bf16x8 a = *(const bf16x8*)(mrow + kk * 32);
        bf16x8 b0 = *(const bf16x8*)(Wlbf + (size_t)(nf0 * 16 + l15) * D + kk * 32 + quad * 8);
        bf16x8 b1 = *(const bf16x8*)(Wlbf + (size_t)(nf1 * 16 + l15) * D + kk * 32 + quad * 8);
        c0 = __builtin_amdgcn_mfma_f32_16x16x32_bf16(a, b0, c0, 0, 0, 0);
        c1 = __builtin_amdgcn_mfma_f32_16x16x32_bf16(a, b1, c1, 0, 0, 0);
    }
#pragma unroll
    for (int kk = 0; kk < 4; ++kk) {
        bf16x8 a = *(const bf16x8*)(arowX + kk * 32);
        bf16x8 b0 = *(const bf16x8*)(Wrbf + (size_t)(nf0 * 16 + l15) * D + kk * 32 + quad * 8);
        bf16x8 b1 = *(const bf16x8*)(Wrbf + (size_t)(nf1 * 16 + l15) * D + kk * 32 + quad * 8);
        c0 = __builtin_amdgcn_mfma_f32_16x16x32_bf16(a, b0, c0, 0, 0, 0);
        c1 = __builtin_amdgcn_mfma_f32_16x16x32_bf16(a, b1, c1, 0, 0, 0);
    }

#pragma unroll
    for (int j = 0; j < 2; ++j) {
        floatx4 c = j ? c1 : c0;
        int f = (wv * 2 + j) * 16 + l15;
        float bv = bias[f];
#pragma unroll
        for (int r = 0; r < 4; ++r) {
            float v = c[r] + bv;
            if (RELU) v = v > 0.f ? v : 0.2f * v;
            int node = node0 + quad * 4 + r;
            if (OUT_BF16)
                ((unsigned short*)outp)[(size_t)node * D + f] = (unsigned short)f2bf(v);
            else
                ((float*)outp)[(size_t)node * D + f] = v;
        }
    }
}

// ---------------- host launch ----------------

extern "C" void kernel_launch(void* const* d_in, const int* in_sizes, int n_in,
                              void* d_out, int out_size, void* d_ws, size_t ws_size,
                              hipStream_t stream) {
    (void)in_sizes; (void)n_in; (void)out_size; (void)ws_size;

    const float* x   = (const float*)d_in[0];
    const int*   ei  = (const int*)d_in[1];
    const float* W1l = (const float*)d_in[2];
    const float* b1  = (const float*)d_in[3];
    const float* W1r = (const float*)d_in[4];
    const float* W2l = (const float*)d_in[5];
    const float* b2  = (const float*)d_in[6];
    const float* W2r = (const float*)d_in[7];

    const int* src = ei;
    const int* dst = ei + N_EDGES;

    char* ws = (char*)d_ws;
    int*   cnt     = (int*)(ws + 0);                 // 200,000 B
    int*   off     = (int*)(ws + 200064);            // 200,004 B
    int*   cursor  = (int*)(ws + 400128);            // 200,000 B
    int*   partial = (int*)(ws + 600192);            // 1,024 B
    int*   ebuf    = (int*)(ws + 601216);            // 2,400,000 B
    unsigned short* wbf = (unsigned short*)(ws + 3001216);   // 131,072 B
    unsigned short* xbf = (unsigned short*)(ws + 3132288);   // 12,800,000 B
    unsigned short* hbf = (unsigned short*)(ws + 15932288);  // 12,800,000 B
    float* out = (float*)d_out;

    unsigned short* w1l_bf = wbf;
    unsigned short* w1r_bf = wbf + 16384;
    unsigned short* w2l_bf = wbf + 32768;
    unsigned short* w2r_bf = wbf + 49152;

    hipMemsetAsync(cnt, 0, N_NODES * sizeof(int), stream);
    k_prep<<<8850, 256, 0, stream>>>(x, xbf, W1l, W1r, W2l, W2r, wbf, dst, cnt);
    k_scan1<<<SCAN_BLOCKS, 256, 0, stream>>>(cnt, off, partial);
    k_scan2<<<1, 256, 0, stream>>>(partial);
    k_scan3<<<SCAN_BLOCKS, 256, 0, stream>>>(off, partial, cursor);
    k_bucket<<<(N_EDGES + 255) / 256, 256, 0, stream>>>(src, dst, cursor, ebuf);

    k_gather_layer<true, true><<<N_NODES / 16, 256, 0, stream>>>(
        off, ebuf, xbf, w1l_bf, b1, w1r_bf, (void*)hbf);
    k_gather_layer<false, false><<<N_NODES / 16, 256, 0, stream>>>(
        off, ebuf, hbf, w2l_bf, b2, w2r_bf, (void*)out);
}

// Round 10
// 268.543 us; speedup vs baseline: 3.7160x; 3.7160x over previous
//
#include <hip/hip_runtime.h>

#define N_NODES 50000
#define N_EDGES 600000
#define D 128
#define SCAN_BLOCKS ((N_NODES + 255) / 256)   // 196

typedef __attribute__((ext_vector_type(8))) short bf16x8;
typedef __attribute__((ext_vector_type(4))) float floatx4;

__device__ inline unsigned int f2bf(float f) {
    unsigned int u = __float_as_uint(f);
    return (u + 0x7FFFu + ((u >> 16) & 1u)) >> 16;   // RNE
}
__device__ inline float bf_lo(unsigned int u) { return __uint_as_float(u << 16); }
__device__ inline float bf_hi(unsigned int u) { return __uint_as_float(u & 0xFFFF0000u); }

// ---------------- fused prep: cvt x -> bf16, cvt W -> bf16, degree count ----
__global__ void k_prep(const float* __restrict__ x, unsigned short* __restrict__ xbf,
                       const float* __restrict__ wa, const float* __restrict__ wb,
                       const float* __restrict__ wc, const float* __restrict__ wd,
                       unsigned short* __restrict__ wbf,
                       const int* __restrict__ dst, int* __restrict__ cnt) {
    const int b = blockIdx.x;
    const int t = threadIdx.x;
    if (b < 6250) {
        int i = b * 256 + t;
        float4 v = ((const float4*)x)[i];
        uint2 o;
        o.x = f2bf(v.x) | (f2bf(v.y) << 16);
        o.y = f2bf(v.z) | (f2bf(v.w) << 16);
        ((uint2*)xbf)[i] = o;
    } else if (b < 6506) {
        int i = (b - 6250) * 256 + t;
        const float* srcs[4] = {wa, wb, wc, wd};
        wbf[i] = (unsigned short)f2bf(srcs[i >> 14][i & 16383]);
    } else {
        int e = (b - 6506) * 256 + t;
        if (e < N_EDGES) atomicAdd(&cnt[dst[e]], 1);
    }
}

// ---------------- CSR scan + bucket ----------------

__global__ void k_scan1(const int* __restrict__ cnt, int* __restrict__ off,
                        int* __restrict__ partial) {
    __shared__ int sdata[256];
    const int t = threadIdx.x;
    const int i = blockIdx.x * 256 + t;
    int v = (i < N_NODES) ? cnt[i] : 0;
    sdata[t] = v;
    __syncthreads();
    for (int d = 1; d < 256; d <<= 1) {
        int u = (t >= d) ? sdata[t - d] : 0;
        __syncthreads();
        sdata[t] += u;
        __syncthreads();
    }
    if (i < N_NODES) off[i] = sdata[t] - v;
    if (t == 255) partial[blockIdx.x] = sdata[255];
}

__global__ void k_scan2(int* __restrict__ partial) {
    __shared__ int sdata[256];
    const int t = threadIdx.x;
    int v = (t < SCAN_BLOCKS) ? partial[t] : 0;
    sdata[t] = v;
    __syncthreads();
    for (int d = 1; d < 256; d <<= 1) {
        int u = (t >= d) ? sdata[t - d] : 0;
        __syncthreads();
        sdata[t] += u;
        __syncthreads();
    }
    if (t < SCAN_BLOCKS) partial[t] = sdata[t] - v;
}

__global__ void k_scan3(int* __restrict__ off, const int* __restrict__ partial,
                        int* __restrict__ cursor) {
    const int i = blockIdx.x * 256 + threadIdx.x;
    if (i < N_NODES) {
        int o = off[i] + partial[blockIdx.x];
        off[i] = o;
        cursor[i] = o;
    }
    if (i == 0) off[N_NODES] = N_EDGES;
}

__global__ void k_bucket(const int* __restrict__ src, const int* __restrict__ dst,
                         int* __restrict__ cursor, int* __restrict__ ebuf) {
    int e = blockIdx.x * blockDim.x + threadIdx.x;
    if (e < N_EDGES) {
        int p = atomicAdd(&cursor[dst[e]], 1);
        ebuf[p] = src[e];
    }
}

// ---------------- fused gather + MFMA layer ----------------
// Block = 256 threads = 16 nodes.
// Phase 1 (wave-quad gather): wave wv handles nodes wv*4..wv*4+3 one at a time.
//   Lanes = 4 edge-slots x 16 chunks: round r loads 4 edges' 256B rows at once
//   (coalesced), register fp32 accumulate, unroll x2. Rounds/wave =
//   sum_i ceil(deg_i/4) ~ 13 (vs max-degree 22 in per-thread scheme). Slot
//   reduce = 2 shfl_xor stages, no LDS atomics.
// Phase 2 (MFMA): unchanged R7-validated: wave wv = feats [32wv,32wv+32),
//   A(mean) from LDS bf16 tile, A(x)/B(W rows) from global.
template <bool RELU, bool OUT_BF16>
__global__ void __launch_bounds__(256) k_gather_layer(
    const int* __restrict__ off, const int* __restrict__ ebuf,
    const unsigned short* __restrict__ Xbf,
    const unsigned short* __restrict__ Wlbf, const float* __restrict__ bias,
    const unsigned short* __restrict__ Wrbf, void* __restrict__ outp) {
    __shared__ int s_off[17];
    __shared__ unsigned short tile[16][136];

    const int t = threadIdx.x;
    const int node0 = blockIdx.x * 16;
    const int lane = t & 63;
    const int wv = t >> 6;
    const int slot = lane >> 4;    // edge slot 0..3
    const int q = lane & 15;       // 16B chunk

    if (t < 17) s_off[t] = off[node0 + t];
    __syncthreads();

    // ---- phase 1: wave-quad gather ----
#pragma unroll
    for (int i = 0; i < 4; ++i) {
        const int nl = wv * 4 + i;
        const int s0 = s_off[nl], s1 = s_off[nl + 1];
        float acc[8] = {0.f, 0.f, 0.f, 0.f, 0.f, 0.f, 0.f, 0.f};
        int e = s0 + slot;
        for (; e + 4 < s1; e += 8) {           // two rounds per iteration
            int sa = ebuf[e];
            int sb = ebuf[e + 4];
            uint4 va = *(const uint4*)(Xbf + (size_t)sa * D + q * 8);
            uint4 vb = *(const uint4*)(Xbf + (size_t)sb * D + q * 8);
            acc[0] += bf_lo(va.x) + bf_lo(vb.x);
            acc[1] += bf_hi(va.x) + bf_hi(vb.x);
            acc[2] += bf_lo(va.y) + bf_lo(vb.y);
            acc[3] += bf_hi(va.y) + bf_hi(vb.y);
            acc[4] += bf_lo(va.z) + bf_lo(vb.z);
            acc[5] += bf_hi(va.z) + bf_hi(vb.z);
            acc[6] += bf_lo(va.w) + bf_lo(vb.w);
            acc[7] += bf_hi(va.w) + bf_hi(vb.w);
        }
        if (e < s1) {
            int sa = ebuf[e];
            uint4 va = *(const uint4*)(Xbf + (size_t)sa * D + q * 8);
            acc[0] += bf_lo(va.x); acc[1] += bf_hi(va.x);
            acc[2] += bf_lo(va.y); acc[3] += bf_hi(va.y);
            acc[4] += bf_lo(va.z); acc[5] += bf_hi(va.z);
            acc[6] += bf_lo(va.w); acc[7] += bf_hi(va.w);
        }
        // reduce across the 4 slots (all lanes end with the sum)
#pragma unroll
        for (int j = 0; j < 8; ++j) {
            acc[j] += __shfl_xor(acc[j], 16, 64);
            acc[j] += __shfl_xor(acc[j], 32, 64);
        }
        if (slot == 0) {
            int deg = s1 - s0;
            float inv = (deg > 0) ? 1.0f / (float)deg : 0.0f;
            uint4 o;
            o.x = f2bf(acc[0] * inv) | (f2bf(acc[1] * inv) << 16);
            o.y = f2bf(acc[2] * inv) | (f2bf(acc[3] * inv) << 16);
            o.z = f2bf(acc[4] * inv) | (f2bf(acc[5] * inv) << 16);
            o.w = f2bf(acc[6] * inv) | (f2bf(acc[7] * inv) << 16);
            *(uint4*)(&tile[nl][q * 8]) = o;
        }
    }
    __syncthreads();

    // ---- phase 2: MFMA ----
    const int l15 = lane & 15;
    const int quad = lane >> 4;

    floatx4 c0 = (floatx4)(0.f), c1 = (floatx4)(0.f);
    const int nf0 = wv * 2, nf1 = wv * 2 + 1;

    const unsigned short* mrow = &tile[l15][quad * 8];
    const unsigned short* arowX = Xbf + (size_t)(node0 + l15) * D + quad * 8;

#pragma unroll
    for (int kk = 0; kk < 4; ++kk) {
        bf16x8 a = *(const bf16x8*)(mrow + kk * 32);
        bf16x8 b0 = *(const bf16x8*)(Wlbf + (size_t)(nf0 * 16 + l15) * D + kk * 32 + quad * 8);
        bf16x8 b1 = *(const bf16x8*)(Wlbf + (size_t)(nf1 * 16 + l15) * D + kk * 32 + quad * 8);
        c0 = __builtin_amdgcn_mfma_f32_16x16x32_bf16(a, b0, c0, 0, 0, 0);
        c1 = __builtin_amdgcn_mfma_f32_16x16x32_bf16(a, b1, c1, 0, 0, 0);
    }
#pragma unroll
    for (int kk = 0; kk < 4; ++kk) {
        bf16x8 a = *(const bf16x8*)(arowX + kk * 32);
        bf16x8 b0 = *(const bf16x8*)(Wrbf + (size_t)(nf0 * 16 + l15) * D + kk * 32 + quad * 8);
        bf16x8 b1 = *(const bf16x8*)(Wrbf + (size_t)(nf1 * 16 + l15) * D + kk * 32 + quad * 8);
        c0 = __builtin_amdgcn_mfma_f32_16x16x32_bf16(a, b0, c0, 0, 0, 0);
        c1 = __builtin_amdgcn_mfma_f32_16x16x32_bf16(a, b1, c1, 0, 0, 0);
    }

#pragma unroll
    for (int j = 0; j < 2; ++j) {
        floatx4 c = j ? c1 : c0;
        int f = (wv * 2 + j) * 16 + l15;
        float bv = bias[f];
#pragma unroll
        for (int r = 0; r < 4; ++r) {
            float v = c[r] + bv;
            if (RELU) v = v > 0.f ? v : 0.2f * v;
            int node = node0 + quad * 4 + r;
            if (OUT_BF16)
                ((unsigned short*)outp)[(size_t)node * D + f] = (unsigned short)f2bf(v);
            else
                ((float*)outp)[(size_t)node * D + f] = v;
        }
    }
}

// ---------------- host launch ----------------

extern "C" void kernel_launch(void* const* d_in, const int* in_sizes, int n_in,
                              void* d_out, int out_size, void* d_ws, size_t ws_size,
                              hipStream_t stream) {
    (void)in_sizes; (void)n_in; (void)out_size; (void)ws_size;

    const float* x   = (const float*)d_in[0];
    const int*   ei  = (const int*)d_in[1];
    const float* W1l = (const float*)d_in[2];
    const float* b1  = (const float*)d_in[3];
    const float* W1r = (const float*)d_in[4];
    const float* W2l = (const float*)d_in[5];
    const float* b2  = (const float*)d_in[6];
    const float* W2r = (const float*)d_in[7];

    const int* src = ei;
    const int* dst = ei + N_EDGES;

    char* ws = (char*)d_ws;
    int*   cnt     = (int*)(ws + 0);                 // 200,000 B
    int*   off     = (int*)(ws + 200064);            // 200,004 B
    int*   cursor  = (int*)(ws + 400128);            // 200,000 B
    int*   partial = (int*)(ws + 600192);            // 1,024 B
    int*   ebuf    = (int*)(ws + 601216);            // 2,400,000 B
    unsigned short* wbf = (unsigned short*)(ws + 3001216);   // 131,072 B
    unsigned short* xbf = (unsigned short*)(ws + 3132288);   // 12,800,000 B
    unsigned short* hbf = (unsigned short*)(ws + 15932288);  // 12,800,000 B
    float* out = (float*)d_out;

    unsigned short* w1l_bf = wbf;
    unsigned short* w1r_bf = wbf + 16384;
    unsigned short* w2l_bf = wbf + 32768;
    unsigned short* w2r_bf = wbf + 49152;

    hipMemsetAsync(cnt, 0, N_NODES * sizeof(int), stream);
    k_prep<<<8850, 256, 0, stream>>>(x, xbf, W1l, W1r, W2l, W2r, wbf, dst, cnt);
    k_scan1<<<SCAN_BLOCKS, 256, 0, stream>>>(cnt, off, partial);
    k_scan2<<<1, 256, 0, stream>>>(partial);
    k_scan3<<<SCAN_BLOCKS, 256, 0, stream>>>(off, partial, cursor);
    k_bucket<<<(N_EDGES + 255) / 256, 256, 0, stream>>>(src, dst, cursor, ebuf);

    k_gather_layer<true, true><<<N_NODES / 16, 256, 0, stream>>>(
        off, ebuf, xbf, w1l_bf, b1, w1r_bf, (void*)hbf);
    k_gather_layer<false, false><<<N_NODES / 16, 256, 0, stream>>>(
        off, ebuf, hbf, w2l_bf, b2, w2r_bf, (void*)out);
}